// Round 8
// baseline (893.639 us; speedup 1.0000x reference)
//
#include <hip/hip_runtime.h>
#include <stdint.h>

#define B_ 2
#define N_ 4096
#define KNN 16
#define D_ 256
#define EPS_ 1e-5f
#define COLS_TOTAL (B_ * N_ * KNN)   // 131072

typedef unsigned short u16;
typedef unsigned long long u64;
typedef __bf16 bf16x8 __attribute__((ext_vector_type(8)));
typedef float f32x4 __attribute__((ext_vector_type(4)));

__device__ __forceinline__ float bu2f(u16 u) { return __uint_as_float(((unsigned)u) << 16); }
__device__ __forceinline__ u16 f2bu(float f) {
  unsigned u = __float_as_uint(f);
  unsigned r = (u + 0x7FFFu + ((u >> 16) & 1u)) >> 16;   // RNE
  return (u16)r;
}
__device__ __forceinline__ float rdl(const void* p, size_t i, int f) {
  return f ? bu2f(((const u16*)p)[i]) : ((const float*)p)[i];
}

// ---------- dtype detect ----------
__global__ void detect_dtype(const unsigned* __restrict__ p, int* __restrict__ flag) {
  __shared__ int cnt;
  if (threadIdx.x == 0) cnt = 0;
  __syncthreads();
  unsigned w = p[threadIdx.x];
  unsigned e = (w >> 7) & 0xFFu;
  if (e >= 0x7Au && e <= 0x81u) atomicAdd(&cnt, 1);
  __syncthreads();
  if (threadIdx.x == 0) *flag = (cnt >= 128) ? 1 : 0;
}

// ---------- ingest ----------
#define NSEG 29
struct Seg { const void* s; float* d; int n; };
struct SegTab { Seg seg[NSEG]; };
__global__ void ingest(SegTab t, const int* __restrict__ flagp, int total) {
  int tid = blockIdx.x * blockDim.x + threadIdx.x;
  if (tid >= total) return;
  int f = *flagp;
  int acc = 0, k = 0;
  for (k = 0; k < NSEG; k++) { if (tid < acc + t.seg[k].n) break; acc += t.seg[k].n; }
  int i = tid - acc;
  t.seg[k].d[i] = rdl(t.seg[k].s, i, f);
}

// ---------- compose q/k/v chain (3 fused, 4-way ILP) ----------
struct C3 { const float* Wo[3]; const float* Wi[3]; const float* bi[3]; const float* bo[3];
            u16* Wout[3]; float* bout[3]; };
__global__ void compose3(C3 c) {
  int z = blockIdx.y;
  int tid = blockIdx.x * blockDim.x + threadIdx.x;
  const float* Wo = c.Wo[z]; const float* Wi = c.Wi[z];
  if (tid < 256 * 128) {
    int o = tid >> 7, i = tid & 127;
    float a0 = 0.f, a1 = 0.f, a2 = 0.f, a3 = 0.f;
    for (int d = 0; d < 256; d += 4) {
      a0 += Wo[o * 256 + d + 0] * Wi[(d + 0) * 128 + i];
      a1 += Wo[o * 256 + d + 1] * Wi[(d + 1) * 128 + i];
      a2 += Wo[o * 256 + d + 2] * Wi[(d + 2) * 128 + i];
      a3 += Wo[o * 256 + d + 3] * Wi[(d + 3) * 128 + i];
    }
    c.Wout[z][o * 128 + i] = f2bu((a0 + a1) + (a2 + a3));
  } else if (tid < 256 * 128 + 256) {
    int o = tid - 256 * 128;
    float a = c.bo[z][o];
    for (int d = 0; d < 256; d++) a += Wo[o * 256 + d] * c.bi[z][d];
    c.bout[z][o] = a;
  }
}

__global__ void quant(const float* __restrict__ s, u16* __restrict__ d, int n) {
  int t = blockIdx.x * blockDim.x + threadIdx.x;
  if (t < n) d[t] = f2bu(s[t]);
}

// ---------- scal (canonical f32) offsets ----------
#define SC_POS 0
#define SC_BLSQ 24576
#define SC_BLSO 24832
#define SC_BK 25088
#define SC_BQ 25344
#define SC_BV 25600
#define SC_WP1 25856
#define SC_BP1 26048
#define SC_G1 26112
#define SC_BT1 26176
#define SC_M1 26240
#define SC_V1 26304
#define SC_BP2 26368
#define SC_BA1 26624
#define SC_G2 27648
#define SC_BT2 28672
#define SC_M2 29696
#define SC_V2 30720
#define SC_BA2 31744
#define SC_BFIN 32000
#define SC_BQP 32128
#define SC_BKP 32384
#define SC_BVP 32640
// folded BN constants (bnprep)
#define SC_W1S 32896   // 192: Wp1 * sc1
#define SC_C1  33088   // 64
#define SC_ASC 33152   // 1024
#define SC_ASH 34176   // 1024
#define SC_TOT 35200

__global__ void bnprep(float* __restrict__ scal) {
  int t = blockIdx.x * blockDim.x + threadIdx.x;
  if (t < 1024) {
    float sc = scal[SC_G2 + t] * (1.0f / sqrtf(scal[SC_V2 + t] + EPS_));
    scal[SC_ASC + t] = sc;
    scal[SC_ASH + t] = scal[SC_BA1 + t] * sc + (scal[SC_BT2 + t] - scal[SC_M2 + t] * sc);
  }
  if (t < 64) {
    float sc1 = scal[SC_G1 + t] * (1.0f / sqrtf(scal[SC_V1 + t] + EPS_));
    scal[SC_C1 + t] = scal[SC_BP1 + t] * sc1 + (scal[SC_BT1 + t] - scal[SC_M1 + t] * sc1);
    for (int i = 0; i < 3; i++) scal[SC_W1S + t * 3 + i] = scal[SC_WP1 + t * 3 + i] * sc1;
  }
}

// ---------- transpose+quantize raw (B,128,N) -> (B*N,128) bf16 ; two tensors fused ----------
struct T2 { const void* src[2]; u16* dst[2]; };
__global__ void transq2(T2 t2, const int* __restrict__ flagp) {
  __shared__ u16 t[32][33];
  int f = *flagp;
  int tensor = blockIdx.z >> 1, b = blockIdx.z & 1;
  const void* raw = t2.src[tensor];
  u16* out = t2.dst[tensor];
  int c0 = blockIdx.y * 32, n0 = blockIdx.x * 32;
  int j = threadIdx.x & 31, i0 = threadIdx.x >> 5;
  for (int s = 0; s < 32; s += 8) {
    int i = i0 + s;
    t[i][j] = f2bu(rdl(raw, ((size_t)b * 128 + c0 + i) * N_ + n0 + j, f));
  }
  __syncthreads();
  int i = threadIdx.x & 31, j0 = threadIdx.x >> 5;
  for (int s = 0; s < 32; s += 8) {
    int jj = j0 + s;
    out[((size_t)b * N_ + n0 + jj) * 128 + c0 + i] = t[i][jj];
  }
}

// ---------- KNN ----------
__device__ __forceinline__ void knn_insert(u64* best, u64 key) {
#pragma unroll
  for (int j = 0; j < KNN; j++) {
    u64 old = best[j];
    bool lt = key < old;
    best[j] = lt ? key : old;
    key = lt ? old : key;
  }
}
__device__ __forceinline__ u64 knn_key(const float* px, float qx, float qy, float qz,
                                       float sqn, int m) {
  float cx = px[m], cy = px[N_ + m], cz = px[2 * N_ + m];
  float sqm = cx * cx + cy * cy + cz * cz;
  float dot = qx * cx + qy * cy + qz * cz;
  float d = (sqn + sqm) - 2.0f * dot;
  unsigned ub = __float_as_uint(d);
  ub = ((int)ub < 0) ? ~ub : (ub | 0x80000000u);
  return ((u64)ub << 32) | (unsigned)m;
}

__global__ void knn_partial(const float* __restrict__ pos, u64* __restrict__ part, int lognchk) {
  int nchk = 1 << lognchk;
  int tid = blockIdx.x * blockDim.x + threadIdx.x;
  if (tid >= (B_ * N_) << lognchk) return;
  int n = tid & (N_ - 1);
  int ch = (tid >> 12) & (nchk - 1);
  int b = tid >> (12 + lognchk);
  const float* px = pos + (size_t)b * 3 * N_;
  float qx = px[n], qy = px[N_ + n], qz = px[2 * N_ + n];
  float sqn = qx * qx + qy * qy + qz * qz;
  u64 best[KNN];
#pragma unroll
  for (int i = 0; i < KNN; i++) best[i] = ~0ull;
  int clen = N_ >> lognchk;
  int m0 = ch * clen;
  for (int m = m0; m < m0 + clen; ++m) knn_insert(best, knn_key(px, qx, qy, qz, sqn, m));
  u64* o = part + (size_t)tid * KNN;
#pragma unroll
  for (int i = 0; i < KNN; i++) o[i] = best[i];
}

__global__ void knn_merge(const u64* __restrict__ part, int* __restrict__ idx, int lognchk) {
  int tid = blockIdx.x * blockDim.x + threadIdx.x;
  if (tid >= B_ * N_) return;
  int n = tid & (N_ - 1);
  int b = tid >> 12;
  int nchk = 1 << lognchk;
  u64 best[KNN];
#pragma unroll
  for (int i = 0; i < KNN; i++) best[i] = ~0ull;
  for (int ch = 0; ch < nchk; ch++) {
    const u64* p = part + ((((size_t)((b << lognchk) + ch)) << 12) + n) * KNN;
    for (int e = 0; e < KNN; e++) knn_insert(best, p[e]);
  }
  int* o = idx + (size_t)tid * KNN;
#pragma unroll
  for (int i = 0; i < KNN; i++) o[i] = (int)(best[i] & 0xffffffffu);
}

__global__ void knn_full(const float* __restrict__ pos, int* __restrict__ idx) {
  int tid = blockIdx.x * blockDim.x + threadIdx.x;
  if (tid >= B_ * N_) return;
  int n = tid & (N_ - 1);
  int b = tid >> 12;
  const float* px = pos + (size_t)b * 3 * N_;
  float qx = px[n], qy = px[N_ + n], qz = px[2 * N_ + n];
  float sqn = qx * qx + qy * qy + qz * qz;
  u64 best[KNN];
#pragma unroll
  for (int i = 0; i < KNN; i++) best[i] = ~0ull;
  for (int m = 0; m < N_; ++m) knn_insert(best, knn_key(px, qx, qy, qz, sqn, m));
  int* o = idx + (size_t)tid * KNN;
#pragma unroll
  for (int i = 0; i < KNN; i++) o[i] = (int)(best[i] & 0xffffffffu);
}

// ---------- q/k/v projection GEMMs (3 fused) ----------
struct G3 { const u16* W[3]; const u16* Bsrc[3]; u16* O[3]; const float* bias[3]; };
__global__ __launch_bounds__(256) void gemm_bt3(G3 g, int M, int K) {
  const int z = blockIdx.z;
  const u16* Wg = g.W[z];
  const u16* Bg = g.Bsrc[z];
  u16* Out = g.O[z];
  const float* bias = g.bias[z];
  __shared__ __align__(16) u16 As[128 * 32];
  __shared__ __align__(16) u16 Bs[128 * 32];
  const int tid = threadIdx.x;
  const int mtile = blockIdx.y, ctile = blockIdx.x;
  const int wid = tid >> 6, lane = tid & 63;
  const int wm = wid >> 1, wc = wid & 1;
  const int l15 = lane & 15, quad = lane >> 4;
  f32x4 acc[4][4];
#pragma unroll
  for (int a = 0; a < 4; a++)
#pragma unroll
    for (int bb = 0; bb < 4; bb++) acc[a][bb] = (f32x4){0.f, 0.f, 0.f, 0.f};
  const int r0 = tid >> 2, q0 = tid & 3;
  for (int k0 = 0; k0 < K; k0 += 32) {
    __syncthreads();
    *(uint4*)(&As[(r0) * 32 + q0 * 8]) = *(const uint4*)(&Wg[((size_t)mtile * 128 + r0) * K + k0 + q0 * 8]);
    *(uint4*)(&As[(r0 + 64) * 32 + q0 * 8]) = *(const uint4*)(&Wg[((size_t)mtile * 128 + r0 + 64) * K + k0 + q0 * 8]);
    *(uint4*)(&Bs[(r0) * 32 + q0 * 8]) = *(const uint4*)(&Bg[((size_t)ctile * 128 + r0) * K + k0 + q0 * 8]);
    *(uint4*)(&Bs[(r0 + 64) * 32 + q0 * 8]) = *(const uint4*)(&Bg[((size_t)ctile * 128 + r0 + 64) * K + k0 + q0 * 8]);
    __syncthreads();
    bf16x8 af[4], bfr[4];
#pragma unroll
    for (int i = 0; i < 4; i++) {
      af[i] = *(const bf16x8*)(&As[(wm * 64 + i * 16 + l15) * 32 + quad * 8]);
      bfr[i] = *(const bf16x8*)(&Bs[(wc * 64 + i * 16 + l15) * 32 + quad * 8]);
    }
#pragma unroll
    for (int mi = 0; mi < 4; mi++)
#pragma unroll
      for (int ni = 0; ni < 4; ni++)
        acc[mi][ni] = __builtin_amdgcn_mfma_f32_16x16x32_bf16(af[mi], bfr[ni], acc[mi][ni], 0, 0, 0);
  }
  const int mbase = mtile * 128 + wm * 64;
  const int cbase = ctile * 128 + wc * 64;
#pragma unroll
  for (int mi = 0; mi < 4; mi++) {
#pragma unroll
    for (int ni = 0; ni < 4; ni++) {
      int m0 = mbase + mi * 16 + quad * 4;
      int c = cbase + ni * 16 + l15;
      u16 pk[4];
#pragma unroll
      for (int r = 0; r < 4; r++) pk[r] = f2bu(acc[mi][ni][r] + bias[m0 + r]);
      *(uint2*)(&Out[(size_t)c * M + m0]) = *(uint2*)pk;
    }
  }
}

// ================= MEGA v3: weights direct-from-global (L2-hot), LDS 51.2 KB =================
// 64 columns (4 points) per block, 512 threads (8 waves: 4 wmg x 2 wcg).
// LDS: XS (64 x 264 u16: pe -> X -> attn), HS (64 x 136 u16: h1 stride 72 -> h stride 136;
//      aliased by aggs f32[1024] after the hb loop).
#define XS_OFF 0
#define HS_OFF 16896
#define SM_TOT 25600     // u16 -> 51,200 B

__global__ __launch_bounds__(512, 6) void mega(
    const float* __restrict__ scal, const int* __restrict__ idx,
    const u16* __restrict__ query_t, const u16* __restrict__ key_t,
    const u16* __restrict__ value_t, u16* __restrict__ pe_g,
    float* __restrict__ out,
    const u16* __restrict__ Wp2g, const u16* __restrict__ Wa1g,
    const u16* __restrict__ Wa2g, const u16* __restrict__ Weg) {
  __shared__ __align__(16) u16 sm[SM_TOT];
  float* aggs = (float*)&sm[HS_OFF];   // alias: HS dead after hb loop
  const int tid = threadIdx.x;
  const int w = tid >> 6, lane = tid & 63;
  const int l15 = lane & 15, quad = lane >> 4;
  const int gcol0 = blockIdx.x * 64;
  const int b = gcol0 >> 16;
  const int n0 = (gcol0 & 65535) >> 4;
  const int wmg = w & 3, wcg = w >> 2;

  // ---- Phase 0: h1 -> HS (stride 72) ----
  {
    int col = tid >> 3, jg = (tid & 7) * 8;
    int n = n0 + (col >> 4), k = col & 15;
    int id = idx[((size_t)(b * N_ + n)) * KNN + k];
    const float* px = scal + SC_POS + (size_t)b * 3 * N_;
    float pr0 = px[n] - px[id];
    float pr1 = px[N_ + n] - px[N_ + id];
    float pr2 = px[2 * N_ + n] - px[2 * N_ + id];
    u16 o[8];
#pragma unroll
    for (int e = 0; e < 8; e++) {
      int j = jg + e;
      float v = scal[SC_W1S + j * 3] * pr0 + scal[SC_W1S + j * 3 + 1] * pr1 +
                scal[SC_W1S + j * 3 + 2] * pr2 + scal[SC_C1 + j];
      o[e] = f2bu(fmaxf(v, 0.f));
    }
    *(uint4*)(&sm[HS_OFF + col * 72 + jg]) = *(uint4*)o;
  }
  __syncthreads();

  // ---- Phase 1: P2 -> pe into XS (af direct from global) ----
  {
    f32x4 pacc[4][2];
#pragma unroll
    for (int mi = 0; mi < 4; mi++)
#pragma unroll
      for (int ni = 0; ni < 2; ni++) pacc[mi][ni] = (f32x4){0.f, 0.f, 0.f, 0.f};
#pragma unroll
    for (int k0 = 0; k0 < 64; k0 += 32) {
      bf16x8 bfr[2];
#pragma unroll
      for (int ni = 0; ni < 2; ni++)
        bfr[ni] = *(const bf16x8*)(&sm[HS_OFF + (wcg * 32 + ni * 16 + l15) * 72 + k0 + quad * 8]);
#pragma unroll
      for (int mi = 0; mi < 4; mi++) {
        bf16x8 af = *(const bf16x8*)(Wp2g + (size_t)(wmg * 64 + mi * 16 + l15) * 64 + k0 + quad * 8);
#pragma unroll
        for (int ni = 0; ni < 2; ni++)
          pacc[mi][ni] = __builtin_amdgcn_mfma_f32_16x16x32_bf16(af, bfr[ni], pacc[mi][ni], 0, 0, 0);
      }
    }
    __syncthreads();   // h1 reads done; XS writes next (XS unused before, but keeps order w/ phase 2)
#pragma unroll
    for (int mi = 0; mi < 4; mi++)
#pragma unroll
      for (int ni = 0; ni < 2; ni++) {
        int m0 = wmg * 64 + mi * 16 + quad * 4;
        int col = wcg * 32 + ni * 16 + l15;
        u16 pk[4];
#pragma unroll
        for (int r = 0; r < 4; r++) pk[r] = f2bu(pacc[mi][ni][r] + scal[SC_BP2 + m0 + r]);
        *(uint2*)(&sm[XS_OFF + col * 264 + m0]) = *(uint2*)pk;
      }
  }
  __syncthreads();

  // ---- Phase 2: pe -> pe_g ; X = query - key_gather + pe -> XS ----
  {
    uint4 xbuf[4];
#pragma unroll
    for (int it = 0; it < 4; it++) {
      int g = tid + it * 512;
      int col = g >> 5, dg = (g & 31) * 8;
      int n = n0 + (col >> 4), k = col & 15;
      int id = idx[((size_t)(b * N_ + n)) * KNN + k];
      uint4 pu = *(const uint4*)(&sm[XS_OFF + col * 264 + dg]);
      *(uint4*)(pe_g + ((size_t)(gcol0 + col)) * D_ + dg) = pu;
      uint4 qu = *(const uint4*)(query_t + ((size_t)(b * N_ + n)) * D_ + dg);
      uint4 ku = *(const uint4*)(key_t + ((size_t)(b * N_ + id)) * D_ + dg);
      const u16 *qs = (const u16*)&qu, *ks = (const u16*)&ku, *ps = (const u16*)&pu;
      u16 o[8];
#pragma unroll
      for (int e = 0; e < 8; e++) o[e] = f2bu((bu2f(qs[e]) - bu2f(ks[e])) + bu2f(ps[e]));
      xbuf[it] = *(uint4*)o;
    }
    __syncthreads();
#pragma unroll
    for (int it = 0; it < 4; it++) {
      int g = tid + it * 512;
      int col = g >> 5, dg = (g & 31) * 8;
      *(uint4*)(&sm[XS_OFF + col * 264 + dg]) = xbuf[it];
    }
  }
  __syncthreads();

  // ---- Phase 3/4: A1 + A2, weights direct from global (L2-hot), no k-loop barriers ----
  f32x4 aacc[4][2];
#pragma unroll
  for (int mi = 0; mi < 4; mi++)
#pragma unroll
    for (int ni = 0; ni < 2; ni++) aacc[mi][ni] = (f32x4){0.f, 0.f, 0.f, 0.f};

  for (int hb = 0; hb < 8; hb++) {
    f32x4 hacc[2][2];
#pragma unroll
    for (int mi = 0; mi < 2; mi++)
#pragma unroll
      for (int ni = 0; ni < 2; ni++) hacc[mi][ni] = (f32x4){0.f, 0.f, 0.f, 0.f};
#pragma unroll 2
    for (int k0 = 0; k0 < 256; k0 += 32) {
      bf16x8 af[2], bx[2];
#pragma unroll
      for (int mi = 0; mi < 2; mi++)
        af[mi] = *(const bf16x8*)(Wa1g + (size_t)(hb * 128 + wmg * 32 + mi * 16 + l15) * 256 + k0 + quad * 8);
#pragma unroll
      for (int ni = 0; ni < 2; ni++)
        bx[ni] = *(const bf16x8*)(&sm[XS_OFF + (wcg * 32 + ni * 16 + l15) * 264 + k0 + quad * 8]);
#pragma unroll
      for (int mi = 0; mi < 2; mi++)
#pragma unroll
        for (int ni = 0; ni < 2; ni++)
          hacc[mi][ni] = __builtin_amdgcn_mfma_f32_16x16x32_bf16(af[mi], bx[ni], hacc[mi][ni], 0, 0, 0);
    }
    __syncthreads();   // all waves done reading HS (prev hb's A2) before overwrite
#pragma unroll
    for (int mi = 0; mi < 2; mi++)
#pragma unroll
      for (int ni = 0; ni < 2; ni++) {
        int hr0 = wmg * 32 + mi * 16 + quad * 4;
        int mh = hb * 128 + hr0;
        int col = wcg * 32 + ni * 16 + l15;
        u16 pk[4];
#pragma unroll
        for (int r = 0; r < 4; r++) {
          float v = hacc[mi][ni][r] * scal[SC_ASC + mh + r] + scal[SC_ASH + mh + r];
          pk[r] = f2bu(fmaxf(v, 0.f));
        }
        *(uint2*)(&sm[HS_OFF + col * 136 + hr0]) = *(uint2*)pk;
      }
    __syncthreads();
#pragma unroll 2
    for (int k0 = 0; k0 < 128; k0 += 32) {
      bf16x8 af[4], bh[2];
#pragma unroll
      for (int mi = 0; mi < 4; mi++)
        af[mi] = *(const bf16x8*)(Wa2g + (size_t)(wmg * 64 + mi * 16 + l15) * 1024 + hb * 128 + k0 + quad * 8);
#pragma unroll
      for (int ni = 0; ni < 2; ni++)
        bh[ni] = *(const bf16x8*)(&sm[HS_OFF + (wcg * 32 + ni * 16 + l15) * 136 + k0 + quad * 8]);
#pragma unroll
      for (int mi = 0; mi < 4; mi++)
#pragma unroll
        for (int ni = 0; ni < 2; ni++)
          aacc[mi][ni] = __builtin_amdgcn_mfma_f32_16x16x32_bf16(af[mi], bh[ni], aacc[mi][ni], 0, 0, 0);
    }
  }

  // ---- Phase 5: attn (+ba2) -> XS ----
#pragma unroll
  for (int mi = 0; mi < 4; mi++)
#pragma unroll
    for (int ni = 0; ni < 2; ni++) {
      int m0 = wmg * 64 + mi * 16 + quad * 4;
      int col = wcg * 32 + ni * 16 + l15;
      u16 pk[4];
#pragma unroll
      for (int r = 0; r < 4; r++) pk[r] = f2bu(aacc[mi][ni][r] + scal[SC_BA2 + m0 + r]);
      *(uint2*)(&sm[XS_OFF + col * 264 + m0]) = *(uint2*)pk;
    }
  __syncthreads();   // attn visible; also: all A2 HS-reads done -> aggs may alias HS

  // ---- Phase 6: softmax + aggregate ----
#pragma unroll
  for (int it = 0; it < 2; it++) {
    int e = tid + it * 512;
    int m = e >> 2, pt = e & 3;
    float a[16];
#pragma unroll
    for (int k = 0; k < 16; k++) a[k] = bu2f(sm[XS_OFF + (pt * 16 + k) * 264 + m]);
    float mx = a[0];
#pragma unroll
    for (int k = 1; k < 16; k++) mx = fmaxf(mx, a[k]);
    float s = 0.f;
#pragma unroll
    for (int k = 0; k < 16; k++) { a[k] = expf(a[k] - mx); s += a[k]; }
    float inv = 1.0f / s;
    float acc = 0.f;
#pragma unroll
    for (int k = 0; k < 16; k++)
      acc += (a[k] * inv) * bu2f(pe_g[((size_t)(gcol0 + pt * 16 + k)) * D_ + m]);
    float val = bu2f(value_t[((size_t)(b * N_ + n0 + pt)) * D_ + m]);
    aggs[m * 4 + pt] = val + acc;
  }
  __syncthreads();

  // ---- Phase 7: linear_end ----
  {
    int ci = tid >> 2, pt = tid & 3;
    float acc = scal[SC_BFIN + ci];
    const u16* wr = Weg + (size_t)ci * 256;
    for (int m8 = 0; m8 < 256; m8 += 8) {
      uint4 wu = *(const uint4*)(wr + m8);
      const u16* ws = (const u16*)&wu;
#pragma unroll
      for (int e = 0; e < 8; e++) acc += bu2f(ws[e]) * aggs[(m8 + e) * 4 + pt];
    }
    out[((size_t)(b * 128 + ci)) * N_ + n0 + pt] = acc;
  }
}

// wtmp (f32) offsets
#define WT_LSQ 0
#define WT_LSO 32768
#define WT_K 65536
#define WT_Q 131072
#define WT_V 196608
#define WT_P2 262144
#define WT_A1 278528
#define WT_A2 540672
#define WT_E 802816
#define WT_TOT 835584
// wbf (bf16) offsets
#define WB_QP 0
#define WB_KP 32768
#define WB_VP 65536
#define WB_P2 98304
#define WB_A1 114688
#define WB_A2 376832
#define WB_E 638976
#define WB_TOT 671744

extern "C" void kernel_launch(void* const* d_in, const int* in_sizes, int n_in,
                              void* d_out, int out_size, void* d_ws, size_t ws_size,
                              hipStream_t stream) {
  (void)in_sizes; (void)n_in; (void)out_size;
  char* wsb = (char*)d_ws;
  size_t off = 0;
  auto alloc = [&](size_t bytes) -> void* {
    void* p = wsb + off;
    off = (off + bytes + 255) & ~(size_t)255;
    return p;
  };
  // persistent (~83 MB incl. pe_g)
  int* flag = (int*)alloc(256);
  int* idx = (int*)alloc((size_t)B_ * N_ * KNN * 4);
  u16* wbf = (u16*)alloc((size_t)WB_TOT * 2);
  float* scal = (float*)alloc((size_t)SC_TOT * 4);
  u16* key_t = (u16*)alloc((size_t)B_ * N_ * D_ * 2);
  u16* query_t = (u16*)alloc((size_t)B_ * N_ * D_ * 2);
  u16* value_t = (u16*)alloc((size_t)B_ * N_ * D_ * 2);
  u16* pe_g = (u16*)alloc((size_t)COLS_TOTAL * D_ * 2);   // 67 MB
  size_t persist = off;
  size_t avail = (ws_size > persist) ? (ws_size - persist) : 0;

  // overlay: wtmp -> qp_t/obj_t -> knn_part
  char* ovl = wsb + persist;
  float* wtmp = (float*)ovl;
  u16* qp_t = (u16*)ovl;
  u16* obj_t = (u16*)(ovl + (size_t)B_ * N_ * 128 * 2 + 256);
  u64* knn_part = (u64*)ovl;

  int lognchk = -1;
  for (int lg = 3; lg >= 0; lg--) {
    if ((((size_t)B_ * N_ * KNN * 8) << lg) <= avail) { lognchk = lg; break; }
  }

  // 1. dtype flag
  detect_dtype<<<1, 256, 0, stream>>>((const unsigned*)d_in[1], flag);

  // 2. ingest canonical f32
  SegTab st;
  int si = 0;
  auto seg = [&](int di, float* d, int n) { st.seg[si].s = d_in[di]; st.seg[si].d = d; st.seg[si].n = n; si++; };
  seg(1, scal + SC_POS, 24576);
  seg(4, scal + SC_BLSQ, 256); seg(6, scal + SC_BLSO, 256);
  seg(8, scal + SC_BK, 256); seg(10, scal + SC_BQ, 256); seg(12, scal + SC_BV, 256);
  seg(13, scal + SC_WP1, 192); seg(14, scal + SC_BP1, 64); seg(15, scal + SC_G1, 64);
  seg(16, scal + SC_BT1, 64); seg(17, scal + SC_M1, 64); seg(18, scal + SC_V1, 64);
  seg(20, scal + SC_BP2, 256); seg(22, scal + SC_BA1, 1024);
  seg(23, scal + SC_G2, 1024); seg(24, scal + SC_BT2, 1024); seg(25, scal + SC_M2, 1024);
  seg(26, scal + SC_V2, 1024); seg(28, scal + SC_BA2, 256); seg(30, scal + SC_BFIN, 128);
  seg(3, wtmp + WT_LSQ, 32768); seg(5, wtmp + WT_LSO, 32768);
  seg(7, wtmp + WT_K, 65536); seg(9, wtmp + WT_Q, 65536); seg(11, wtmp + WT_V, 65536);
  seg(19, wtmp + WT_P2, 16384); seg(21, wtmp + WT_A1, 262144);
  seg(27, wtmp + WT_A2, 262144); seg(29, wtmp + WT_E, 32768);
  int total = 32128 + WT_TOT;
  ingest<<<(total + 255) / 256, 256, 0, stream>>>(st, flag, total);

  // 3. fold BN + compose q/k/v + quantize
  bnprep<<<4, 256, 0, stream>>>(scal);
  C3 c3;
  c3.Wo[0] = wtmp + WT_Q; c3.Wi[0] = wtmp + WT_LSQ; c3.bi[0] = scal + SC_BLSQ; c3.bo[0] = scal + SC_BQ;
  c3.Wout[0] = wbf + WB_QP; c3.bout[0] = scal + SC_BQP;
  c3.Wo[1] = wtmp + WT_K; c3.Wi[1] = wtmp + WT_LSO; c3.bi[1] = scal + SC_BLSO; c3.bo[1] = scal + SC_BK;
  c3.Wout[1] = wbf + WB_KP; c3.bout[1] = scal + SC_BKP;
  c3.Wo[2] = wtmp + WT_V; c3.Wi[2] = wtmp + WT_LSO; c3.bi[2] = scal + SC_BLSO; c3.bo[2] = scal + SC_BV;
  c3.Wout[2] = wbf + WB_VP; c3.bout[2] = scal + SC_BVP;
  compose3<<<dim3(130, 3), 256, 0, stream>>>(c3);
  quant<<<(573440 + 255) / 256, 256, 0, stream>>>(wtmp + WT_P2, wbf + WB_P2, 573440);

  // 4. transpose inputs (wtmp dead)
  T2 t2;
  t2.src[0] = d_in[2]; t2.dst[0] = qp_t;
  t2.src[1] = d_in[0]; t2.dst[1] = obj_t;
  transq2<<<dim3(N_ / 32, 4, 4), 256, 0, stream>>>(t2, flag);

  // 5. q/k/v projections (composed, K=128), one fused launch
  G3 g3;
  g3.W[0] = wbf + WB_QP; g3.Bsrc[0] = qp_t;  g3.O[0] = query_t; g3.bias[0] = scal + SC_BQP;
  g3.W[1] = wbf + WB_KP; g3.Bsrc[1] = obj_t; g3.O[1] = key_t;   g3.bias[1] = scal + SC_BKP;
  g3.W[2] = wbf + WB_VP; g3.Bsrc[2] = obj_t; g3.O[2] = value_t; g3.bias[2] = scal + SC_BVP;
  gemm_bt3<<<dim3(B_ * N_ / 128, 2, 3), 256, 0, stream>>>(g3, 256, 128);

  // 6. KNN
  if (lognchk >= 0) {
    knn_partial<<<((B_ * N_) << lognchk) / 256, 256, 0, stream>>>(scal + SC_POS, knn_part, lognchk);
    knn_merge<<<(B_ * N_) / 256, 256, 0, stream>>>(knn_part, idx, lognchk);
  } else {
    knn_full<<<(B_ * N_) / 256, 256, 0, stream>>>(scal + SC_POS, idx);
  }

  // 7. MEGA fused pipeline
  mega<<<COLS_TOTAL / 64, 512, 0, stream>>>(
      scal, idx, query_t, key_t, value_t, pe_g, (float*)d_out,
      wbf + WB_P2, wbf + WB_A1, wbf + WB_A2, wbf + WB_E);
}

// Round 9
// 562.429 us; speedup vs baseline: 1.5889x; 1.5889x over previous
//
#include <hip/hip_runtime.h>
#include <stdint.h>

#define B_ 2
#define N_ 4096
#define KNN 16
#define D_ 256
#define EPS_ 1e-5f
#define COLS_TOTAL (B_ * N_ * KNN)   // 131072

typedef unsigned short u16;
typedef unsigned long long u64;
typedef __bf16 bf16x8 __attribute__((ext_vector_type(8)));
typedef float f32x4 __attribute__((ext_vector_type(4)));

__device__ __forceinline__ float bu2f(u16 u) { return __uint_as_float(((unsigned)u) << 16); }
__device__ __forceinline__ u16 f2bu(float f) {
  unsigned u = __float_as_uint(f);
  unsigned r = (u + 0x7FFFu + ((u >> 16) & 1u)) >> 16;   // RNE
  return (u16)r;
}
__device__ __forceinline__ float rdl(const void* p, size_t i, int f) {
  return f ? bu2f(((const u16*)p)[i]) : ((const float*)p)[i];
}

// ---------- dtype detect ----------
__global__ void detect_dtype(const unsigned* __restrict__ p, int* __restrict__ flag) {
  __shared__ int cnt;
  if (threadIdx.x == 0) cnt = 0;
  __syncthreads();
  unsigned w = p[threadIdx.x];
  unsigned e = (w >> 7) & 0xFFu;
  if (e >= 0x7Au && e <= 0x81u) atomicAdd(&cnt, 1);
  __syncthreads();
  if (threadIdx.x == 0) *flag = (cnt >= 128) ? 1 : 0;
}

// ---------- ingest ----------
#define NSEG 29
struct Seg { const void* s; float* d; int n; };
struct SegTab { Seg seg[NSEG]; };
__global__ void ingest(SegTab t, const int* __restrict__ flagp, int total) {
  int tid = blockIdx.x * blockDim.x + threadIdx.x;
  if (tid >= total) return;
  int f = *flagp;
  int acc = 0, k = 0;
  for (k = 0; k < NSEG; k++) { if (tid < acc + t.seg[k].n) break; acc += t.seg[k].n; }
  int i = tid - acc;
  t.seg[k].d[i] = rdl(t.seg[k].s, i, f);
}

// ---------- compose q/k/v chain ----------
struct C3 { const float* Wo[3]; const float* Wi[3]; const float* bi[3]; const float* bo[3];
            u16* Wout[3]; float* bout[3]; };
__global__ void compose3(C3 c) {
  int z = blockIdx.y;
  int tid = blockIdx.x * blockDim.x + threadIdx.x;
  const float* Wo = c.Wo[z]; const float* Wi = c.Wi[z];
  if (tid < 256 * 128) {
    int o = tid >> 7, i = tid & 127;
    float a0 = 0.f, a1 = 0.f, a2 = 0.f, a3 = 0.f;
    for (int d = 0; d < 256; d += 4) {
      a0 += Wo[o * 256 + d + 0] * Wi[(d + 0) * 128 + i];
      a1 += Wo[o * 256 + d + 1] * Wi[(d + 1) * 128 + i];
      a2 += Wo[o * 256 + d + 2] * Wi[(d + 2) * 128 + i];
      a3 += Wo[o * 256 + d + 3] * Wi[(d + 3) * 128 + i];
    }
    c.Wout[z][o * 128 + i] = f2bu((a0 + a1) + (a2 + a3));
  } else if (tid < 256 * 128 + 256) {
    int o = tid - 256 * 128;
    float a = c.bo[z][o];
    for (int d = 0; d < 256; d++) a += Wo[o * 256 + d] * c.bi[z][d];
    c.bout[z][o] = a;
  }
}

__global__ void quant(const float* __restrict__ s, u16* __restrict__ d, int n) {
  int t = blockIdx.x * blockDim.x + threadIdx.x;
  if (t < n) d[t] = f2bu(s[t]);
}

// ---------- fragment-linear weight quantize ----------
// layout: tile (mt, kc) of 16 rows x 32 k; within tile, lane(l15=lane&15, quad=lane>>4)
// holds W[mt*16+l15][kc*32+quad*8 .. +7] at flin[tile*512 + lane*8 + j]
struct QF { const float* src[3]; u16* dst[3]; int M[3]; int K[3]; };
__global__ void quant_flin(QF q) {
  int z = blockIdx.y;
  int g = blockIdx.x * blockDim.x + threadIdx.x;
  int M = q.M[z], K = q.K[z];
  if (g >= (M * K) / 8) return;
  int tile = g >> 6, lane = g & 63;
  int l15 = lane & 15, quad = lane >> 4;
  int kt = K >> 5;
  int mt = tile / kt, kc = tile % kt;
  const float* s = q.src[z] + (size_t)(mt * 16 + l15) * K + kc * 32 + quad * 8;
  u16* d = q.dst[z] + (size_t)g * 8;
  u16 o[8];
#pragma unroll
  for (int j = 0; j < 8; j++) o[j] = f2bu(s[j]);
  *(uint4*)d = *(uint4*)o;
}

// ---------- scal (canonical f32) offsets ----------
#define SC_POS 0
#define SC_BLSQ 24576
#define SC_BLSO 24832
#define SC_BK 25088
#define SC_BQ 25344
#define SC_BV 25600
#define SC_WP1 25856
#define SC_BP1 26048
#define SC_G1 26112
#define SC_BT1 26176
#define SC_M1 26240
#define SC_V1 26304
#define SC_BP2 26368
#define SC_BA1 26624
#define SC_G2 27648
#define SC_BT2 28672
#define SC_M2 29696
#define SC_V2 30720
#define SC_BA2 31744
#define SC_BFIN 32000
#define SC_BQP 32128
#define SC_BKP 32384
#define SC_BVP 32640
#define SC_W1S 32896
#define SC_C1  33088
#define SC_ASC 33152
#define SC_ASH 34176
#define SC_TOT 35200

__global__ void bnprep(float* __restrict__ scal) {
  int t = blockIdx.x * blockDim.x + threadIdx.x;
  if (t < 1024) {
    float sc = scal[SC_G2 + t] * (1.0f / sqrtf(scal[SC_V2 + t] + EPS_));
    scal[SC_ASC + t] = sc;
    scal[SC_ASH + t] = scal[SC_BA1 + t] * sc + (scal[SC_BT2 + t] - scal[SC_M2 + t] * sc);
  }
  if (t < 64) {
    float sc1 = scal[SC_G1 + t] * (1.0f / sqrtf(scal[SC_V1 + t] + EPS_));
    scal[SC_C1 + t] = scal[SC_BP1 + t] * sc1 + (scal[SC_BT1 + t] - scal[SC_M1 + t] * sc1);
    for (int i = 0; i < 3; i++) scal[SC_W1S + t * 3 + i] = scal[SC_WP1 + t * 3 + i] * sc1;
  }
}

// ---------- transpose+quantize (two tensors fused) ----------
struct T2 { const void* src[2]; u16* dst[2]; };
__global__ void transq2(T2 t2, const int* __restrict__ flagp) {
  __shared__ u16 t[32][33];
  int f = *flagp;
  int tensor = blockIdx.z >> 1, b = blockIdx.z & 1;
  const void* raw = t2.src[tensor];
  u16* out = t2.dst[tensor];
  int c0 = blockIdx.y * 32, n0 = blockIdx.x * 32;
  int j = threadIdx.x & 31, i0 = threadIdx.x >> 5;
  for (int s = 0; s < 32; s += 8) {
    int i = i0 + s;
    t[i][j] = f2bu(rdl(raw, ((size_t)b * 128 + c0 + i) * N_ + n0 + j, f));
  }
  __syncthreads();
  int i = threadIdx.x & 31, j0 = threadIdx.x >> 5;
  for (int s = 0; s < 32; s += 8) {
    int jj = j0 + s;
    out[((size_t)b * N_ + n0 + jj) * 128 + c0 + i] = t[i][jj];
  }
}

// ---------- KNN ----------
__device__ __forceinline__ void knn_insert(u64* best, u64 key) {
#pragma unroll
  for (int j = 0; j < KNN; j++) {
    u64 old = best[j];
    bool lt = key < old;
    best[j] = lt ? key : old;
    key = lt ? old : key;
  }
}
__device__ __forceinline__ u64 knn_key(const float* px, float qx, float qy, float qz,
                                       float sqn, int m) {
  float cx = px[m], cy = px[N_ + m], cz = px[2 * N_ + m];
  float sqm = cx * cx + cy * cy + cz * cz;
  float dot = qx * cx + qy * cy + qz * cz;
  float d = (sqn + sqm) - 2.0f * dot;
  unsigned ub = __float_as_uint(d);
  ub = ((int)ub < 0) ? ~ub : (ub | 0x80000000u);
  return ((u64)ub << 32) | (unsigned)m;
}

__global__ void knn_partial(const float* __restrict__ pos, u64* __restrict__ part, int lognchk) {
  int nchk = 1 << lognchk;
  int tid = blockIdx.x * blockDim.x + threadIdx.x;
  if (tid >= (B_ * N_) << lognchk) return;
  int n = tid & (N_ - 1);
  int ch = (tid >> 12) & (nchk - 1);
  int b = tid >> (12 + lognchk);
  const float* px = pos + (size_t)b * 3 * N_;
  float qx = px[n], qy = px[N_ + n], qz = px[2 * N_ + n];
  float sqn = qx * qx + qy * qy + qz * qz;
  u64 best[KNN];
#pragma unroll
  for (int i = 0; i < KNN; i++) best[i] = ~0ull;
  int clen = N_ >> lognchk;
  int m0 = ch * clen;
  for (int m = m0; m < m0 + clen; ++m) knn_insert(best, knn_key(px, qx, qy, qz, sqn, m));
  u64* o = part + (size_t)tid * KNN;
#pragma unroll
  for (int i = 0; i < KNN; i++) o[i] = best[i];
}

__global__ void knn_merge(const u64* __restrict__ part, int* __restrict__ idx, int lognchk) {
  int tid = blockIdx.x * blockDim.x + threadIdx.x;
  if (tid >= B_ * N_) return;
  int n = tid & (N_ - 1);
  int b = tid >> 12;
  int nchk = 1 << lognchk;
  u64 best[KNN];
#pragma unroll
  for (int i = 0; i < KNN; i++) best[i] = ~0ull;
  for (int ch = 0; ch < nchk; ch++) {
    const u64* p = part + ((((size_t)((b << lognchk) + ch)) << 12) + n) * KNN;
    for (int e = 0; e < KNN; e++) knn_insert(best, p[e]);
  }
  int* o = idx + (size_t)tid * KNN;
#pragma unroll
  for (int i = 0; i < KNN; i++) o[i] = (int)(best[i] & 0xffffffffu);
}

__global__ void knn_full(const float* __restrict__ pos, int* __restrict__ idx) {
  int tid = blockIdx.x * blockDim.x + threadIdx.x;
  if (tid >= B_ * N_) return;
  int n = tid & (N_ - 1);
  int b = tid >> 12;
  const float* px = pos + (size_t)b * 3 * N_;
  float qx = px[n], qy = px[N_ + n], qz = px[2 * N_ + n];
  float sqn = qx * qx + qy * qy + qz * qz;
  u64 best[KNN];
#pragma unroll
  for (int i = 0; i < KNN; i++) best[i] = ~0ull;
  for (int m = 0; m < N_; ++m) knn_insert(best, knn_key(px, qx, qy, qz, sqn, m));
  int* o = idx + (size_t)tid * KNN;
#pragma unroll
  for (int i = 0; i < KNN; i++) o[i] = (int)(best[i] & 0xffffffffu);
}

// ---------- q/k/v projection GEMMs (3 fused, proven) ----------
struct G3 { const u16* W[3]; const u16* Bsrc[3]; u16* O[3]; const float* bias[3]; };
__global__ __launch_bounds__(256) void gemm_bt3(G3 g, int M, int K) {
  const int z = blockIdx.z;
  const u16* Wg = g.W[z];
  const u16* Bg = g.Bsrc[z];
  u16* Out = g.O[z];
  const float* bias = g.bias[z];
  __shared__ __align__(16) u16 As[128 * 32];
  __shared__ __align__(16) u16 Bs[128 * 32];
  const int tid = threadIdx.x;
  const int mtile = blockIdx.y, ctile = blockIdx.x;
  const int wid = tid >> 6, lane = tid & 63;
  const int wm = wid >> 1, wc = wid & 1;
  const int l15 = lane & 15, quad = lane >> 4;
  f32x4 acc[4][4];
#pragma unroll
  for (int a = 0; a < 4; a++)
#pragma unroll
    for (int bb = 0; bb < 4; bb++) acc[a][bb] = (f32x4){0.f, 0.f, 0.f, 0.f};
  const int r0 = tid >> 2, q0 = tid & 3;
  for (int k0 = 0; k0 < K; k0 += 32) {
    __syncthreads();
    *(uint4*)(&As[(r0) * 32 + q0 * 8]) = *(const uint4*)(&Wg[((size_t)mtile * 128 + r0) * K + k0 + q0 * 8]);
    *(uint4*)(&As[(r0 + 64) * 32 + q0 * 8]) = *(const uint4*)(&Wg[((size_t)mtile * 128 + r0 + 64) * K + k0 + q0 * 8]);
    *(uint4*)(&Bs[(r0) * 32 + q0 * 8]) = *(const uint4*)(&Bg[((size_t)ctile * 128 + r0) * K + k0 + q0 * 8]);
    *(uint4*)(&Bs[(r0 + 64) * 32 + q0 * 8]) = *(const uint4*)(&Bg[((size_t)ctile * 128 + r0 + 64) * K + k0 + q0 * 8]);
    __syncthreads();
    bf16x8 af[4], bfr[4];
#pragma unroll
    for (int i = 0; i < 4; i++) {
      af[i] = *(const bf16x8*)(&As[(wm * 64 + i * 16 + l15) * 32 + quad * 8]);
      bfr[i] = *(const bf16x8*)(&Bs[(wc * 64 + i * 16 + l15) * 32 + quad * 8]);
    }
#pragma unroll
    for (int mi = 0; mi < 4; mi++)
#pragma unroll
      for (int ni = 0; ni < 4; ni++)
        acc[mi][ni] = __builtin_amdgcn_mfma_f32_16x16x32_bf16(af[mi], bfr[ni], acc[mi][ni], 0, 0, 0);
  }
  const int mbase = mtile * 128 + wm * 64;
  const int cbase = ctile * 128 + wc * 64;
#pragma unroll
  for (int mi = 0; mi < 4; mi++) {
#pragma unroll
    for (int ni = 0; ni < 4; ni++) {
      int m0 = mbase + mi * 16 + quad * 4;
      int c = cbase + ni * 16 + l15;
      u16 pk[4];
#pragma unroll
      for (int r = 0; r < 4; r++) pk[r] = f2bu(acc[mi][ni][r] + bias[m0 + r]);
      *(uint2*)(&Out[(size_t)c * M + m0]) = *(uint2*)pk;
    }
  }
}

// ================= MEGA v4: m-split waves, flin weights from global, barrier-light =================
// 64 cols/block, 512 threads = 8 waves, each wave owns 32 m-rows x all 64 cols.
// hb = 4 slices of 256. LDS: XS 64x264 (pe->X->attn), HS 64x264 (h1 -> h-slice; aggs alias).
#define XS_OFF 0
#define HS_OFF 16896
#define SM_TOT 33792    // u16 -> 67,584 B -> 2 blocks/CU

__global__ __launch_bounds__(512, 4) void mega(
    const float* __restrict__ scal, const int* __restrict__ idx,
    const u16* __restrict__ query_t, const u16* __restrict__ key_t,
    const u16* __restrict__ value_t, u16* __restrict__ pe_g,
    float* __restrict__ out,
    const u16* __restrict__ Wp2f, const u16* __restrict__ Wa1f,
    const u16* __restrict__ Wa2f, const u16* __restrict__ Weg) {
  __shared__ __align__(16) u16 sm[SM_TOT];
  float* aggs = (float*)&sm[HS_OFF];   // alias: HS dead after last A2
  const int tid = threadIdx.x;
  const int w = tid >> 6, lane = tid & 63;
  const int l15 = lane & 15, quad = lane >> 4;
  const int gcol0 = blockIdx.x * 64;
  const int b = gcol0 >> 16;
  const int n0 = (gcol0 & 65535) >> 4;

  // ---- Phase 0: h1 -> HS (stride 264, cols x 64k) ----
  {
    int col = tid >> 3, jg = (tid & 7) * 8;
    int n = n0 + (col >> 4), k = col & 15;
    int id = idx[((size_t)(b * N_ + n)) * KNN + k];
    const float* px = scal + SC_POS + (size_t)b * 3 * N_;
    float pr0 = px[n] - px[id];
    float pr1 = px[N_ + n] - px[N_ + id];
    float pr2 = px[2 * N_ + n] - px[2 * N_ + id];
    u16 o[8];
#pragma unroll
    for (int e = 0; e < 8; e++) {
      int j = jg + e;
      float v = scal[SC_W1S + j * 3] * pr0 + scal[SC_W1S + j * 3 + 1] * pr1 +
                scal[SC_W1S + j * 3 + 2] * pr2 + scal[SC_C1 + j];
      o[e] = f2bu(fmaxf(v, 0.f));
    }
    *(uint4*)(&sm[HS_OFF + col * 264 + jg]) = *(uint4*)o;
  }
  __syncthreads();

  // ---- Phase 1: P2 -> pe into XS. wave: 32 m-rows x 64 n. K=64. ----
  {
    f32x4 pacc[2][4];
#pragma unroll
    for (int mi = 0; mi < 2; mi++)
#pragma unroll
      for (int ni = 0; ni < 4; ni++) pacc[mi][ni] = (f32x4){0.f, 0.f, 0.f, 0.f};
#pragma unroll
    for (int kc = 0; kc < 2; kc++) {
      int k0 = kc * 32;
      bf16x8 af[2], bfr[4];
#pragma unroll
      for (int mi = 0; mi < 2; mi++)
        af[mi] = *(const bf16x8*)(Wp2f + (size_t)((w * 2 + mi) * 2 + kc) * 512 + lane * 8);
#pragma unroll
      for (int ni = 0; ni < 4; ni++)
        bfr[ni] = *(const bf16x8*)(&sm[HS_OFF + (ni * 16 + l15) * 264 + k0 + quad * 8]);
#pragma unroll
      for (int mi = 0; mi < 2; mi++)
#pragma unroll
        for (int ni = 0; ni < 4; ni++)
          pacc[mi][ni] = __builtin_amdgcn_mfma_f32_16x16x32_bf16(af[mi], bfr[ni], pacc[mi][ni], 0, 0, 0);
    }
#pragma unroll
    for (int mi = 0; mi < 2; mi++)
#pragma unroll
      for (int ni = 0; ni < 4; ni++) {
        int m0 = w * 32 + mi * 16 + quad * 4;
        int col = ni * 16 + l15;
        u16 pk[4];
#pragma unroll
        for (int r = 0; r < 4; r++) pk[r] = f2bu(pacc[mi][ni][r] + scal[SC_BP2 + m0 + r]);
        *(uint2*)(&sm[XS_OFF + col * 264 + m0]) = *(uint2*)pk;
      }
  }
  __syncthreads();

  // ---- Phase 2: pe -> pe_g ; X = query - key_gather + pe -> XS ----
  {
    uint4 xbuf[4];
#pragma unroll
    for (int it = 0; it < 4; it++) {
      int g = tid + it * 512;
      int col = g >> 5, dg = (g & 31) * 8;
      int n = n0 + (col >> 4), k = col & 15;
      int id = idx[((size_t)(b * N_ + n)) * KNN + k];
      uint4 pu = *(const uint4*)(&sm[XS_OFF + col * 264 + dg]);
      *(uint4*)(pe_g + ((size_t)(gcol0 + col)) * D_ + dg) = pu;
      uint4 qu = *(const uint4*)(query_t + ((size_t)(b * N_ + n)) * D_ + dg);
      uint4 ku = *(const uint4*)(key_t + ((size_t)(b * N_ + id)) * D_ + dg);
      const u16 *qs = (const u16*)&qu, *ks = (const u16*)&ku, *ps = (const u16*)&pu;
      u16 o[8];
#pragma unroll
      for (int e = 0; e < 8; e++) o[e] = f2bu((bu2f(qs[e]) - bu2f(ks[e])) + bu2f(ps[e]));
      xbuf[it] = *(uint4*)o;
    }
    __syncthreads();
#pragma unroll
    for (int it = 0; it < 4; it++) {
      int g = tid + it * 512;
      int col = g >> 5, dg = (g & 31) * 8;
      *(uint4*)(&sm[XS_OFF + col * 264 + dg]) = xbuf[it];
    }
  }
  __syncthreads();

  // ---- A1/A2 over 4 hb slices of 256 rows ----
  f32x4 aacc[2][4];
#pragma unroll
  for (int mi = 0; mi < 2; mi++)
#pragma unroll
    for (int ni = 0; ni < 4; ni++) aacc[mi][ni] = (f32x4){0.f, 0.f, 0.f, 0.f};

  for (int hb = 0; hb < 4; hb++) {
    // A1: wave rows = hb*256 + w*32 (+mi*16). k over X (256). Barrier-free k-loop.
    f32x4 hacc[2][4];
#pragma unroll
    for (int mi = 0; mi < 2; mi++)
#pragma unroll
      for (int ni = 0; ni < 4; ni++) hacc[mi][ni] = (f32x4){0.f, 0.f, 0.f, 0.f};
#pragma unroll 2
    for (int kc = 0; kc < 8; kc++) {
      int k0 = kc * 32;
      bf16x8 af[2], bx[4];
#pragma unroll
      for (int mi = 0; mi < 2; mi++)
        af[mi] = *(const bf16x8*)(Wa1f + (size_t)((hb * 16 + w * 2 + mi) * 8 + kc) * 512 + lane * 8);
#pragma unroll
      for (int ni = 0; ni < 4; ni++)
        bx[ni] = *(const bf16x8*)(&sm[XS_OFF + (ni * 16 + l15) * 264 + k0 + quad * 8]);
#pragma unroll
      for (int mi = 0; mi < 2; mi++)
#pragma unroll
        for (int ni = 0; ni < 4; ni++)
          hacc[mi][ni] = __builtin_amdgcn_mfma_f32_16x16x32_bf16(af[mi], bx[ni], hacc[mi][ni], 0, 0, 0);
    }
    __syncthreads();   // prior HS readers (h1 / previous A2) done before overwrite
#pragma unroll
    for (int mi = 0; mi < 2; mi++)
#pragma unroll
      for (int ni = 0; ni < 4; ni++) {
        int khb = w * 32 + mi * 16 + quad * 4;
        int mh = hb * 256 + khb;
        int col = ni * 16 + l15;
        u16 pk[4];
#pragma unroll
        for (int r = 0; r < 4; r++) {
          float v = hacc[mi][ni][r] * scal[SC_ASC + mh + r] + scal[SC_ASH + mh + r];
          pk[r] = f2bu(fmaxf(v, 0.f));
        }
        *(uint2*)(&sm[HS_OFF + col * 264 + khb]) = *(uint2*)pk;
      }
    __syncthreads();
    // A2: wave outm = w*32 (+mi*16); k = this hb's 256 h-rows. Barrier-free k-loop.
#pragma unroll 2
    for (int kc = 0; kc < 8; kc++) {
      int k0 = kc * 32;
      bf16x8 af[2], bh[4];
#pragma unroll
      for (int mi = 0; mi < 2; mi++)
        af[mi] = *(const bf16x8*)(Wa2f + (size_t)((w * 2 + mi) * 32 + hb * 8 + kc) * 512 + lane * 8);
#pragma unroll
      for (int ni = 0; ni < 4; ni++)
        bh[ni] = *(const bf16x8*)(&sm[HS_OFF + (ni * 16 + l15) * 264 + k0 + quad * 8]);
#pragma unroll
      for (int mi = 0; mi < 2; mi++)
#pragma unroll
        for (int ni = 0; ni < 4; ni++)
          aacc[mi][ni] = __builtin_amdgcn_mfma_f32_16x16x32_bf16(af[mi], bh[ni], aacc[mi][ni], 0, 0, 0);
    }
  }

  // ---- Phase 5: attn (+ba2) -> XS ----
  __syncthreads();   // all waves done reading XS (A1 used X through last hb)
#pragma unroll
  for (int mi = 0; mi < 2; mi++)
#pragma unroll
    for (int ni = 0; ni < 4; ni++) {
      int m0 = w * 32 + mi * 16 + quad * 4;
      int col = ni * 16 + l15;
      u16 pk[4];
#pragma unroll
      for (int r = 0; r < 4; r++) pk[r] = f2bu(aacc[mi][ni][r] + scal[SC_BA2 + m0 + r]);
      *(uint2*)(&sm[XS_OFF + col * 264 + m0]) = *(uint2*)pk;
    }
  __syncthreads();   // attn visible; HS dead -> aggs alias safe

  // ---- Phase 6: softmax + aggregate ----
#pragma unroll
  for (int it = 0; it < 2; it++) {
    int e = tid + it * 512;
    int m = e >> 2, pt = e & 3;
    float a[16];
#pragma unroll
    for (int k = 0; k < 16; k++) a[k] = bu2f(sm[XS_OFF + (pt * 16 + k) * 264 + m]);
    float mx = a[0];
#pragma unroll
    for (int k = 1; k < 16; k++) mx = fmaxf(mx, a[k]);
    float s = 0.f;
#pragma unroll
    for (int k = 0; k < 16; k++) { a[k] = expf(a[k] - mx); s += a[k]; }
    float inv = 1.0f / s;
    float acc = 0.f;
#pragma unroll
    for (int k = 0; k < 16; k++)
      acc += (a[k] * inv) * bu2f(pe_g[((size_t)(gcol0 + pt * 16 + k)) * D_ + m]);
    float val = bu2f(value_t[((size_t)(b * N_ + n0 + pt)) * D_ + m]);
    aggs[m * 4 + pt] = val + acc;
  }
  __syncthreads();

  // ---- Phase 7: linear_end ----
  {
    int ci = tid >> 2, pt = tid & 3;
    float acc = scal[SC_BFIN + ci];
    const u16* wr = Weg + (size_t)ci * 256;
    for (int m8 = 0; m8 < 256; m8 += 8) {
      uint4 wu = *(const uint4*)(wr + m8);
      const u16* ws = (const u16*)&wu;
#pragma unroll
      for (int e = 0; e < 8; e++) acc += bu2f(ws[e]) * aggs[(m8 + e) * 4 + pt];
    }
    out[((size_t)(b * 128 + ci)) * N_ + n0 + pt] = acc;
  }
}

// wtmp (f32) offsets
#define WT_LSQ 0
#define WT_LSO 32768
#define WT_K 65536
#define WT_Q 131072
#define WT_V 196608
#define WT_P2 262144
#define WT_A1 278528
#define WT_A2 540672
#define WT_E 802816
#define WT_TOT 835584
// wbf (bf16) offsets
#define WB_QP 0
#define WB_KP 32768
#define WB_VP 65536
#define WB_P2 98304
#define WB_A1 114688
#define WB_A2 376832
#define WB_E 638976
#define WB_TOT 671744

extern "C" void kernel_launch(void* const* d_in, const int* in_sizes, int n_in,
                              void* d_out, int out_size, void* d_ws, size_t ws_size,
                              hipStream_t stream) {
  (void)in_sizes; (void)n_in; (void)out_size;
  char* wsb = (char*)d_ws;
  size_t off = 0;
  auto alloc = [&](size_t bytes) -> void* {
    void* p = wsb + off;
    off = (off + bytes + 255) & ~(size_t)255;
    return p;
  };
  int* flag = (int*)alloc(256);
  int* idx = (int*)alloc((size_t)B_ * N_ * KNN * 4);
  u16* wbf = (u16*)alloc((size_t)WB_TOT * 2);
  float* scal = (float*)alloc((size_t)SC_TOT * 4);
  u16* key_t = (u16*)alloc((size_t)B_ * N_ * D_ * 2);
  u16* query_t = (u16*)alloc((size_t)B_ * N_ * D_ * 2);
  u16* value_t = (u16*)alloc((size_t)B_ * N_ * D_ * 2);
  u16* pe_g = (u16*)alloc((size_t)COLS_TOTAL * D_ * 2);   // 67 MB
  size_t persist = off;
  size_t avail = (ws_size > persist) ? (ws_size - persist) : 0;

  char* ovl = wsb + persist;
  float* wtmp = (float*)ovl;
  u16* qp_t = (u16*)ovl;
  u16* obj_t = (u16*)(ovl + (size_t)B_ * N_ * 128 * 2 + 256);
  u64* knn_part = (u64*)ovl;

  int lognchk = -1;
  for (int lg = 3; lg >= 0; lg--) {
    if ((((size_t)B_ * N_ * KNN * 8) << lg) <= avail) { lognchk = lg; break; }
  }

  detect_dtype<<<1, 256, 0, stream>>>((const unsigned*)d_in[1], flag);

  SegTab st;
  int si = 0;
  auto seg = [&](int di, float* d, int n) { st.seg[si].s = d_in[di]; st.seg[si].d = d; st.seg[si].n = n; si++; };
  seg(1, scal + SC_POS, 24576);
  seg(4, scal + SC_BLSQ, 256); seg(6, scal + SC_BLSO, 256);
  seg(8, scal + SC_BK, 256); seg(10, scal + SC_BQ, 256); seg(12, scal + SC_BV, 256);
  seg(13, scal + SC_WP1, 192); seg(14, scal + SC_BP1, 64); seg(15, scal + SC_G1, 64);
  seg(16, scal + SC_BT1, 64); seg(17, scal + SC_M1, 64); seg(18, scal + SC_V1, 64);
  seg(20, scal + SC_BP2, 256); seg(22, scal + SC_BA1, 1024);
  seg(23, scal + SC_G2, 1024); seg(24, scal + SC_BT2, 1024); seg(25, scal + SC_M2, 1024);
  seg(26, scal + SC_V2, 1024); seg(28, scal + SC_BA2, 256); seg(30, scal + SC_BFIN, 128);
  seg(3, wtmp + WT_LSQ, 32768); seg(5, wtmp + WT_LSO, 32768);
  seg(7, wtmp + WT_K, 65536); seg(9, wtmp + WT_Q, 65536); seg(11, wtmp + WT_V, 65536);
  seg(19, wtmp + WT_P2, 16384); seg(21, wtmp + WT_A1, 262144);
  seg(27, wtmp + WT_A2, 262144); seg(29, wtmp + WT_E, 32768);
  int total = 32128 + WT_TOT;
  ingest<<<(total + 255) / 256, 256, 0, stream>>>(st, flag, total);

  bnprep<<<4, 256, 0, stream>>>(scal);
  C3 c3;
  c3.Wo[0] = wtmp + WT_Q; c3.Wi[0] = wtmp + WT_LSQ; c3.bi[0] = scal + SC_BLSQ; c3.bo[0] = scal + SC_BQ;
  c3.Wout[0] = wbf + WB_QP; c3.bout[0] = scal + SC_BQP;
  c3.Wo[1] = wtmp + WT_K; c3.Wi[1] = wtmp + WT_LSO; c3.bi[1] = scal + SC_BLSO; c3.bo[1] = scal + SC_BK;
  c3.Wout[1] = wbf + WB_KP; c3.bout[1] = scal + SC_BKP;
  c3.Wo[2] = wtmp + WT_V; c3.Wi[2] = wtmp + WT_LSO; c3.bi[2] = scal + SC_BLSO; c3.bo[2] = scal + SC_BV;
  c3.Wout[2] = wbf + WB_VP; c3.bout[2] = scal + SC_BVP;
  compose3<<<dim3(130, 3), 256, 0, stream>>>(c3);

  // fragment-linear quantize for Wp2 / Wa1 / Wa2 ; plain for We
  QF qf;
  qf.src[0] = wtmp + WT_P2; qf.dst[0] = wbf + WB_P2; qf.M[0] = 256;  qf.K[0] = 64;
  qf.src[1] = wtmp + WT_A1; qf.dst[1] = wbf + WB_A1; qf.M[1] = 1024; qf.K[1] = 256;
  qf.src[2] = wtmp + WT_A2; qf.dst[2] = wbf + WB_A2; qf.M[2] = 256;  qf.K[2] = 1024;
  quant_flin<<<dim3(128, 3), 256, 0, stream>>>(qf);
  quant<<<128, 256, 0, stream>>>(wtmp + WT_E, wbf + WB_E, 32768);

  T2 t2;
  t2.src[0] = d_in[2]; t2.dst[0] = qp_t;
  t2.src[1] = d_in[0]; t2.dst[1] = obj_t;
  transq2<<<dim3(N_ / 32, 4, 4), 256, 0, stream>>>(t2, flag);

  G3 g3;
  g3.W[0] = wbf + WB_QP; g3.Bsrc[0] = qp_t;  g3.O[0] = query_t; g3.bias[0] = scal + SC_BQP;
  g3.W[1] = wbf + WB_KP; g3.Bsrc[1] = obj_t; g3.O[1] = key_t;   g3.bias[1] = scal + SC_BKP;
  g3.W[2] = wbf + WB_VP; g3.Bsrc[2] = obj_t; g3.O[2] = value_t; g3.bias[2] = scal + SC_BVP;
  gemm_bt3<<<dim3(B_ * N_ / 128, 2, 3), 256, 0, stream>>>(g3, 256, 128);

  if (lognchk >= 0) {
    knn_partial<<<((B_ * N_) << lognchk) / 256, 256, 0, stream>>>(scal + SC_POS, knn_part, lognchk);
    knn_merge<<<(B_ * N_) / 256, 256, 0, stream>>>(knn_part, idx, lognchk);
  } else {
    knn_full<<<(B_ * N_) / 256, 256, 0, stream>>>(scal + SC_POS, idx);
  }

  mega<<<COLS_TOTAL / 64, 512, 0, stream>>>(
      scal, idx, query_t, key_t, value_t, pe_g, (float*)d_out,
      wbf + WB_P2, wbf + WB_A1, wbf + WB_A2, wbf + WB_E);
}